// Round 5
// baseline (2470.304 us; speedup 1.0000x reference)
//
#include <hip/hip_runtime.h>
#include <cstdint>
#include <cstddef>

// Problem constants (fixed by the reference: B=8, S=1024, H=512, 8 speakers, 2 layers)
#define SS 1024
#define HH 512
#define G3 1536  // 3*H

typedef _Float16 half8 __attribute__((ext_vector_type(8)));
typedef float f32x4 __attribute__((ext_vector_type(4)));
typedef unsigned u32x4 __attribute__((ext_vector_type(4)));

// ---- workspace layout (bytes) ----
// Rings are u32 words: (tag << 16) | f16(h); tag = producing round + 1; memset(0)
// encodes "round -1" so round 0 consumes initial zeros with no special case.
// Two copies of each ring: UC (agent-scope, always correct) + MIR (cached, fast
// when all WGs of a speaker share an XCD/L2 -- performance only, with fallback).
static constexpr unsigned OFF_TLIST = 0;                  // [8][8][1024] int
static constexpr unsigned OFF_LEN   = 262144;             // [64] int
static constexpr unsigned OFF_META  = 262400;             // [8] int
static constexpr unsigned OFF_H0UC  = 262656;             // u32[2][64][512]
static constexpr unsigned OFF_H1UC  = OFF_H0UC + 262144;
static constexpr unsigned OFF_H0MIR = OFF_H1UC + 262144;
static constexpr unsigned OFF_H1MIR = OFF_H0MIR + 262144;
static constexpr unsigned WS_NEED   = OFF_H1MIR + 262144; // ~1.28 MB

__device__ __forceinline__ half8 cvt8(const float* p) {
  float4 u = *(const float4*)p;
  float4 v = *(const float4*)(p + 4);
  half8 h;
  h[0]=(_Float16)u.x; h[1]=(_Float16)u.y; h[2]=(_Float16)u.z; h[3]=(_Float16)u.w;
  h[4]=(_Float16)v.x; h[5]=(_Float16)v.y; h[6]=(_Float16)v.z; h[7]=(_Float16)v.w;
  return h;
}

// strip low f16 from 8 tagged u32 words -> half8 (4x v_perm_b32)
__device__ __forceinline__ half8 pack8(u32x4 a, u32x4 b) {
  union { unsigned u[4]; half8 h; } r;
  r.u[0] = __builtin_amdgcn_perm(a[1], a[0], 0x05040100);
  r.u[1] = __builtin_amdgcn_perm(a[3], a[2], 0x05040100);
  r.u[2] = __builtin_amdgcn_perm(b[1], b[0], 0x05040100);
  r.u[3] = __builtin_amdgcn_perm(b[3], b[2], 0x05040100);
  return r.h;
}

__device__ __forceinline__ float sigm(float x) { return 1.f / (1.f + __expf(-x)); }

// 8x dwordx4 loads (64B from each of two ring slices) in ONE asm block.
// MIR variant: sc0 (bypass L1, hit shared XCD L2). UC variant: sc0 sc1 (coherence point).
template <bool UC>
__device__ __forceinline__ void ld8(const unsigned* p0, const unsigned* p1,
                                    u32x4& a0, u32x4& a1, u32x4& a2, u32x4& a3,
                                    u32x4& b0, u32x4& b1, u32x4& b2, u32x4& b3) {
  if constexpr (UC) {
    asm volatile(
      "global_load_dwordx4 %0, %8, off sc0 sc1\n\t"
      "global_load_dwordx4 %1, %8, off offset:16 sc0 sc1\n\t"
      "global_load_dwordx4 %2, %8, off offset:32 sc0 sc1\n\t"
      "global_load_dwordx4 %3, %8, off offset:48 sc0 sc1\n\t"
      "global_load_dwordx4 %4, %9, off sc0 sc1\n\t"
      "global_load_dwordx4 %5, %9, off offset:16 sc0 sc1\n\t"
      "global_load_dwordx4 %6, %9, off offset:32 sc0 sc1\n\t"
      "global_load_dwordx4 %7, %9, off offset:48 sc0 sc1\n\t"
      "s_waitcnt vmcnt(0)"
      : "=&v"(a0), "=&v"(a1), "=&v"(a2), "=&v"(a3),
        "=&v"(b0), "=&v"(b1), "=&v"(b2), "=&v"(b3)
      : "v"(p0), "v"(p1)
      : "memory");
  } else {
    asm volatile(
      "global_load_dwordx4 %0, %8, off sc0\n\t"
      "global_load_dwordx4 %1, %8, off offset:16 sc0\n\t"
      "global_load_dwordx4 %2, %8, off offset:32 sc0\n\t"
      "global_load_dwordx4 %3, %8, off offset:48 sc0\n\t"
      "global_load_dwordx4 %4, %9, off sc0\n\t"
      "global_load_dwordx4 %5, %9, off offset:16 sc0\n\t"
      "global_load_dwordx4 %6, %9, off offset:32 sc0\n\t"
      "global_load_dwordx4 %7, %9, off offset:48 sc0\n\t"
      "s_waitcnt vmcnt(0)"
      : "=&v"(a0), "=&v"(a1), "=&v"(a2), "=&v"(a3),
        "=&v"(b0), "=&v"(b1), "=&v"(b2), "=&v"(b3)
      : "v"(p0), "v"(p1)
      : "memory");
  }
  __builtin_amdgcn_sched_barrier(0);  // keep uses after the waitcnt (rule #18)
}

// ---------------- prep: build per-(sp,b) timestep lists ----------------
__global__ void prep_kernel(const int* __restrict__ spk, int* __restrict__ tlist,
                            int* __restrict__ len, int* __restrict__ meta) {
  __shared__ int slen[64];
  const int t = threadIdx.x;   // 0..63
  const int sp = t >> 3, b = t & 7;
  int cnt = 0;
  int* tl = tlist + (sp * 8 + b) * SS;
  const int4* srow = (const int4*)(spk + b * SS);
#pragma unroll 4
  for (int i = 0; i < SS / 4; ++i) {
    int4 v = srow[i];
    if (v.x == sp) tl[cnt++] = 4 * i + 0;
    if (v.y == sp) tl[cnt++] = 4 * i + 1;
    if (v.z == sp) tl[cnt++] = 4 * i + 2;
    if (v.w == sp) tl[cnt++] = 4 * i + 3;
  }
  len[t] = cnt;
  slen[t] = cnt;
  for (int i = cnt; i < SS; ++i) tl[i] = 0;  // pad so speculative reads are safe
  __syncthreads();
  if (t < 8) {
    int m = 0;
    for (int i = 0; i < 8; ++i) m = max(m, slen[t * 8 + i]);
    meta[t] = m;
  }
}

// ---------------- persistent GRU kernel ----------------
// 256 WGs: sp = wg&7 (-> same XCD under round-robin dispatch), og = wg>>3.
// WG owns outputs j0=og*16 of BOTH layers for speaker sp. No inter-WG barrier:
// ring words carry their round tag; consumers poll the data itself (mirror copy
// in the shared XCD L2; sticky per-WG fallback to the UC copy on timeout).
__launch_bounds__(256, 1)
__global__ void gru_main(const float* __restrict__ x,
                         const float* __restrict__ Wi, const float* __restrict__ Wh,
                         const float* __restrict__ bi, const float* __restrict__ bh,
                         const int* __restrict__ tlist, const int* __restrict__ len,
                         const int* __restrict__ meta,
                         unsigned* __restrict__ h0uc, unsigned* __restrict__ h1uc,
                         unsigned* __restrict__ h0mir, unsigned* __restrict__ h1mir,
                         float* __restrict__ out) {
  const int wg = blockIdx.x;      // 0..255
  const int sp = wg & 7;          // speaker == XCD group under round-robin
  const int og = wg >> 3;         // 0..31
  const int j0 = og * 16;
  const int tid = threadIdx.x;
  const int w  = tid >> 6;        // wave 0..3 (owns K-quarter)
  const int l  = tid & 63;
  const int lr = l & 15;          // A-row (batch) / B-col (weight row in tile)
  const int lg = l >> 4;          // k sub-group
  const int b8 = lr & 7;          // batch row (rows 8-15 duplicate 0-7)

  // accbuf[w][slab][n*20+m]: slabs 0..2 / 3..5 = x-GEMM double buffer,
  // 6..8 = Wh0*h0, 9..11 = Wi1*h0, 12..14 = Wh1*h1.
  __shared__ float accbuf[4][15][320];
  // raw tagged words; pitch 516 -> b128 A-frag reads bank-bijective over (b8,lg)
  __shared__ unsigned hstage[2][8][516];
  __shared__ unsigned fbflag;   // sticky: 1 -> this WG polls the UC copy

  if (tid == 0) fbflag = 0;

  // ---- weight preload: fp32 global -> f16 register fragments (done once) ----
  const size_t WMAT = (size_t)G3 * HH;
  const float* pWi0 = Wi + (size_t)(sp * 2 + 0) * WMAT;
  const float* pWh0 = Wh + (size_t)(sp * 2 + 0) * WMAT;
  const float* pWi1 = Wi + (size_t)(sp * 2 + 1) * WMAT;
  const float* pWh1 = Wh + (size_t)(sp * 2 + 1) * WMAT;

  half8 bwi0[3][4], bwh0[3][4], bwi1[3][4], bwh1[3][4];
#pragma unroll
  for (int T = 0; T < 3; ++T) {
#pragma unroll
    for (int q = 0; q < 4; ++q) {
      const size_t row = (size_t)(T * HH + j0 + lr);
      const int k0 = lg * 8 + (w * 4 + q) * 32;
      bwi0[T][q] = cvt8(pWi0 + row * HH + k0);
      bwh0[T][q] = cvt8(pWh0 + row * HH + k0);
      bwi1[T][q] = cvt8(pWi1 + row * HH + k0);
      bwh1[T][q] = cvt8(pWh1 + row * HH + k0);
    }
  }

  // ---- gate-thread metadata: threads 0..127 = layer0, 128..255 = layer1 ----
  const bool isA = tid < 128;
  const int u_ = isA ? tid : (tid - 128);
  const int gb = u_ >> 4;     // batch
  const int gj = u_ & 15;     // output within group
  const int Lb = len[sp * 8 + gb];
  const int* tlB = tlist + (sp * 8 + gb) * SS;
  float bAi[3], bAh[3], bBi[3], bBh[3];
#pragma unroll
  for (int g = 0; g < 3; ++g) {
    const int n = g * HH + j0 + gj;
    bAi[g] = bi[(sp * 2 + 0) * G3 + n];
    bAh[g] = bh[(sp * 2 + 0) * G3 + n];
    bBi[g] = bi[(sp * 2 + 1) * G3 + n];
    bBh[g] = bh[(sp * 2 + 1) * G3 + n];
  }

  // per-lane x-gather metadata (A row b8 supplies batch b8)
  const int* tlX = tlist + (sp * 8 + b8) * SS;
  const float* xrow_base = x + (size_t)b8 * SS * HH;

  const int maxlen = meta[sp];

  float h0prev = 0.f, h1prev = 0.f;   // recurrent state for (gb, j0+gj)

  // consumer poll layout: thread reads words [tid*16 .. tid*16+15] of the
  // 4096-word speaker slice (chain-major: word = chain*512 + j).
  const unsigned thoff = (unsigned)tid * 16u;
  const int srow_ = tid >> 5;            // chain within speaker
  const int scol_ = (tid & 31) * 16;     // column base

  // ---- prologue: x-GEMM (Wi0 * x_0) into x-slab set 0 ----
  {
    const int tx = tlX[0];
    const float* xs = xrow_base + (size_t)tx * HH;
    half8 xf[4];
    f32x4 a0[3];
#pragma unroll
    for (int T = 0; T < 3; ++T)
#pragma unroll
      for (int e = 0; e < 4; ++e) a0[T][e] = 0.f;
#pragma unroll
    for (int q = 0; q < 4; ++q) xf[q] = cvt8(xs + lg * 8 + (w * 4 + q) * 32);
#pragma unroll
    for (int T = 0; T < 3; ++T)
#pragma unroll
      for (int q = 0; q < 4; ++q)
        a0[T] = __builtin_amdgcn_mfma_f32_16x16x32_f16(xf[q], bwi0[T][q], a0[T], 0, 0, 0);
#pragma unroll
    for (int T = 0; T < 3; ++T)
      *(f32x4*)&accbuf[w][T][lr * 20 + lg * 4] = a0[T];
  }
  __syncthreads();   // fbflag + prologue visible

  for (int r = 0; r <= maxlen; ++r) {
    // ---- A: poll both rings (expect tag r on every word), then stage to LDS ----
    {
      const unsigned exp = (unsigned)r;
      const size_t sl0 = ((size_t)(((r - 1) & 1) * 64 + sp * 8)) * HH + thoff;
      const size_t sl1 = ((size_t)((r & 1) * 64 + sp * 8)) * HH + thoff;
      bool useUC = (fbflag != 0);
      const unsigned* p0 = (useUC ? h0uc : h0mir) + sl0;
      const unsigned* p1 = (useUC ? h1uc : h1mir) + sl1;
      u32x4 a0, a1, a2, a3, c0, c1, c2, c3;
      unsigned iters = 0;
      for (;;) {
        if (useUC) ld8<true>(p0, p1, a0, a1, a2, a3, c0, c1, c2, c3);
        else       ld8<false>(p0, p1, a0, a1, a2, a3, c0, c1, c2, c3);
        unsigned bad = 0;
#pragma unroll
        for (int i = 0; i < 4; ++i) {
          bad |= (a0[i] >> 16) ^ exp; bad |= (a1[i] >> 16) ^ exp;
          bad |= (a2[i] >> 16) ^ exp; bad |= (a3[i] >> 16) ^ exp;
          bad |= (c0[i] >> 16) ^ exp; bad |= (c1[i] >> 16) ^ exp;
          bad |= (c2[i] >> 16) ^ exp; bad |= (c3[i] >> 16) ^ exp;
        }
        if (!bad) break;
        __builtin_amdgcn_s_sleep(1);
        ++iters;
        if (iters == 3000u && !useUC) {       // mirror never converged -> UC forever
          useUC = true; fbflag = 1u;
          p0 = h0uc + sl0; p1 = h1uc + sl1;
        }
        if (iters > 3000000u) break;          // safety against pathological hang
      }
      *(u32x4*)&hstage[0][srow_][scol_ + 0]  = a0;
      *(u32x4*)&hstage[0][srow_][scol_ + 4]  = a1;
      *(u32x4*)&hstage[0][srow_][scol_ + 8]  = a2;
      *(u32x4*)&hstage[0][srow_][scol_ + 12] = a3;
      *(u32x4*)&hstage[1][srow_][scol_ + 0]  = c0;
      *(u32x4*)&hstage[1][srow_][scol_ + 4]  = c1;
      *(u32x4*)&hstage[1][srow_][scol_ + 8]  = c2;
      *(u32x4*)&hstage[1][srow_][scol_ + 12] = c3;
    }
    __syncthreads();   // hstage ready

    // ---- C: A-frags from LDS (strip tags) + 36 MFMA (Wh0*h0, Wi1*h0, Wh1*h1) ----
    half8 hA0[4], hA1[4];
#pragma unroll
    for (int q = 0; q < 4; ++q) {
      const int k0 = lg * 8 + (w * 4 + q) * 32;
      u32x4 t0 = *(const u32x4*)&hstage[0][b8][k0];
      u32x4 t1 = *(const u32x4*)&hstage[0][b8][k0 + 4];
      u32x4 t2 = *(const u32x4*)&hstage[1][b8][k0];
      u32x4 t3 = *(const u32x4*)&hstage[1][b8][k0 + 4];
      hA0[q] = pack8(t0, t1);
      hA1[q] = pack8(t2, t3);
    }
    f32x4 acc[3][3];
#pragma unroll
    for (int Gm = 0; Gm < 3; ++Gm)
#pragma unroll
      for (int T = 0; T < 3; ++T)
#pragma unroll
        for (int e = 0; e < 4; ++e) acc[Gm][T][e] = 0.f;
#pragma unroll
    for (int T = 0; T < 3; ++T) {
#pragma unroll
      for (int q = 0; q < 4; ++q) {
        acc[0][T] = __builtin_amdgcn_mfma_f32_16x16x32_f16(hA0[q], bwh0[T][q], acc[0][T], 0, 0, 0);
        acc[1][T] = __builtin_amdgcn_mfma_f32_16x16x32_f16(hA0[q], bwi1[T][q], acc[1][T], 0, 0, 0);
        acc[2][T] = __builtin_amdgcn_mfma_f32_16x16x32_f16(hA1[q], bwh1[T][q], acc[2][T], 0, 0, 0);
      }
    }
#pragma unroll
    for (int Gm = 0; Gm < 3; ++Gm)
#pragma unroll
      for (int T = 0; T < 3; ++T)
        *(f32x4*)&accbuf[w][6 + Gm * 3 + T][lr * 20 + lg * 4] = acc[Gm][T];
    __syncthreads();   // accbuf complete

    // ---- E: gates; ALWAYS publish tagged word to UC + mirror copies ----
    const int xb = 3 * (r & 1);           // x-slab set for this round
    const int ci = gj * 20 + gb;
    const unsigned tagw = ((unsigned)(r + 1)) << 16;
    if (isA) {
      if (r < Lb) {
        float giv[3], ghv[3];
#pragma unroll
        for (int g = 0; g < 3; ++g) {
          giv[g] = accbuf[0][xb + g][ci] + accbuf[1][xb + g][ci] +
                   accbuf[2][xb + g][ci] + accbuf[3][xb + g][ci] + bAi[g];
          ghv[g] = accbuf[0][6 + g][ci] + accbuf[1][6 + g][ci] +
                   accbuf[2][6 + g][ci] + accbuf[3][6 + g][ci] + bAh[g];
        }
        const float rr = sigm(giv[0] + ghv[0]);
        const float zz = sigm(giv[1] + ghv[1]);
        const float nn = tanhf(giv[2] + rr * ghv[2]);
        h0prev = (1.f - zz) * nn + zz * h0prev;
      }
      union { _Float16 hf; unsigned short us; } cv; cv.hf = (_Float16)h0prev;
      const unsigned word = tagw | (unsigned)cv.us;
      const size_t idx = ((size_t)((r & 1) * 64 + sp * 8 + gb)) * HH + j0 + gj;
      __hip_atomic_store(&h0uc[idx],  word, __ATOMIC_RELAXED, __HIP_MEMORY_SCOPE_AGENT);
      __hip_atomic_store(&h0mir[idx], word, __ATOMIC_RELAXED, __HIP_MEMORY_SCOPE_WORKGROUP);
    } else {
      if ((r >= 1) && (r <= Lb)) {
        float giv[3], ghv[3];
#pragma unroll
        for (int g = 0; g < 3; ++g) {
          giv[g] = accbuf[0][9 + g][ci] + accbuf[1][9 + g][ci] +
                   accbuf[2][9 + g][ci] + accbuf[3][9 + g][ci] + bBi[g];
          ghv[g] = accbuf[0][12 + g][ci] + accbuf[1][12 + g][ci] +
                   accbuf[2][12 + g][ci] + accbuf[3][12 + g][ci] + bBh[g];
        }
        const float rr = sigm(giv[0] + ghv[0]);
        const float zz = sigm(giv[1] + ghv[1]);
        const float nn = tanhf(giv[2] + rr * ghv[2]);
        h1prev = (1.f - zz) * nn + zz * h1prev;
        const int tcur = tlB[(r - 1) & (SS - 1)];
        out[((size_t)(gb * SS + tcur)) * HH + j0 + gj] = h1prev;
      }
      union { _Float16 hf; unsigned short us; } cv; cv.hf = (_Float16)h1prev;
      const unsigned word = tagw | (unsigned)cv.us;
      const size_t idx = ((size_t)(((r - 1) & 1) * 64 + sp * 8 + gb)) * HH + j0 + gj;
      __hip_atomic_store(&h1uc[idx],  word, __ATOMIC_RELAXED, __HIP_MEMORY_SCOPE_AGENT);
      __hip_atomic_store(&h1mir[idx], word, __ATOMIC_RELAXED, __HIP_MEMORY_SCOPE_WORKGROUP);
    }

    // ---- G: x-GEMM (Wi0 * x_{r+1}) into the OTHER x-slab set (no barrier needed:
    //      set (r+1)&1 is disjoint from set r&1 read in E; next round's two
    //      syncthreads separate these writes from their readers) ----
    {
      const int tx = tlX[(r + 1) & (SS - 1)];
      const float* xs = xrow_base + (size_t)tx * HH;
      half8 xf[4];
      f32x4 a0[3];
#pragma unroll
      for (int T = 0; T < 3; ++T)
#pragma unroll
        for (int e = 0; e < 4; ++e) a0[T][e] = 0.f;
#pragma unroll
      for (int q = 0; q < 4; ++q) xf[q] = cvt8(xs + lg * 8 + (w * 4 + q) * 32);
#pragma unroll
      for (int T = 0; T < 3; ++T)
#pragma unroll
        for (int q = 0; q < 4; ++q)
          a0[T] = __builtin_amdgcn_mfma_f32_16x16x32_f16(xf[q], bwi0[T][q], a0[T], 0, 0, 0);
#pragma unroll
      for (int T = 0; T < 3; ++T)
        *(f32x4*)&accbuf[w][3 * ((r + 1) & 1) + T][lr * 20 + lg * 4] = a0[T];
    }
  }
}

extern "C" void kernel_launch(void* const* d_in, const int* in_sizes, int n_in,
                              void* d_out, int out_size, void* d_ws, size_t ws_size,
                              hipStream_t stream) {
  const float* x   = (const float*)d_in[0];
  const int*   spk = (const int*)d_in[1];
  const float* Wi  = (const float*)d_in[2];
  const float* Wh  = (const float*)d_in[3];
  const float* bi  = (const float*)d_in[4];
  const float* bh  = (const float*)d_in[5];
  float* out = (float*)d_out;
  char* ws = (char*)d_ws;

  int*      tlist = (int*)(ws + OFF_TLIST);
  int*      len   = (int*)(ws + OFF_LEN);
  int*      meta  = (int*)(ws + OFF_META);
  unsigned* h0uc  = (unsigned*)(ws + OFF_H0UC);
  unsigned* h1uc  = (unsigned*)(ws + OFF_H1UC);
  unsigned* h0mir = (unsigned*)(ws + OFF_H0MIR);
  unsigned* h1mir = (unsigned*)(ws + OFF_H1MIR);

  (void)in_sizes; (void)n_in; (void)out_size; (void)ws_size;

  // zero both ring copies (tags -> "round -1"); re-done every launch
  hipMemsetAsync(ws + OFF_H0UC, 0, WS_NEED - OFF_H0UC, stream);
  prep_kernel<<<1, 64, 0, stream>>>(spk, tlist, len, meta);
  gru_main<<<256, 256, 0, stream>>>(x, Wi, Wh, bi, bh, tlist, len, meta,
                                    h0uc, h1uc, h0mir, h1mir, out);
}

// Round 6
// 838.856 us; speedup vs baseline: 2.9448x; 2.9448x over previous
//
#include <hip/hip_runtime.h>
#include <cstdint>
#include <cstddef>

// Problem constants (fixed by the reference: B=8, S=1024, H=512, 8 speakers, 2 layers)
#define SS 1024
#define HH 512
#define G3 1536  // 3*H

typedef _Float16 half8 __attribute__((ext_vector_type(8)));
typedef float f32x4 __attribute__((ext_vector_type(4)));
typedef unsigned u32x4 __attribute__((ext_vector_type(4)));

// ---- workspace layout (bytes) ----
// Ring words: (tag<<16) | f16(h). tag = publish round + 1; memset(0) = "round -1".
static constexpr unsigned OFF_TLIST = 0;                 // [8][8][1024] int
static constexpr unsigned OFF_LEN   = 262144;            // [64] int
static constexpr unsigned OFF_META  = 262400;            // [8] int per-speaker max len
static constexpr unsigned OFF_H0    = 262656;            // u32[4][64][512] = 512 KB
static constexpr unsigned OFF_H1    = OFF_H0 + 524288;   // u32[2][64][512] = 256 KB
static constexpr unsigned OFF_PROG  = OFF_H1 + 262144;   // u32[8][16] layer1 progress
static constexpr unsigned WS_NEED   = OFF_PROG + 512;

__device__ __forceinline__ half8 cvt8(const float* p) {
  float4 u = *(const float4*)p;
  float4 v = *(const float4*)(p + 4);
  half8 h;
  h[0]=(_Float16)u.x; h[1]=(_Float16)u.y; h[2]=(_Float16)u.z; h[3]=(_Float16)u.w;
  h[4]=(_Float16)v.x; h[5]=(_Float16)v.y; h[6]=(_Float16)v.z; h[7]=(_Float16)v.w;
  return h;
}

// strip low f16 from 8 tagged u32 words -> half8 (4x v_perm_b32)
__device__ __forceinline__ half8 pack8(u32x4 a, u32x4 b) {
  union { unsigned u[4]; half8 h; } r;
  r.u[0] = __builtin_amdgcn_perm(a[1], a[0], 0x05040100);
  r.u[1] = __builtin_amdgcn_perm(a[3], a[2], 0x05040100);
  r.u[2] = __builtin_amdgcn_perm(b[1], b[0], 0x05040100);
  r.u[3] = __builtin_amdgcn_perm(b[3], b[2], 0x05040100);
  return r.h;
}

__device__ __forceinline__ float sigm(float x) { return 1.f / (1.f + __expf(-x)); }

__device__ __forceinline__ unsigned tagbad(u32x4 v, unsigned exp) {
  return ((v[0] >> 16) ^ exp) | ((v[1] >> 16) ^ exp) |
         ((v[2] >> 16) ^ exp) | ((v[3] >> 16) ^ exp);
}

// device-coherent (sc0 sc1) 16B load, single
__device__ __forceinline__ u32x4 uc_ld16(const unsigned* p) {
  u32x4 d;
  asm volatile("global_load_dwordx4 %0, %1, off sc0 sc1\n\ts_waitcnt vmcnt(0)"
               : "=v"(d) : "v"(p) : "memory");
  __builtin_amdgcn_sched_barrier(0);
  return d;
}

// 4x 16B UC loads, latencies overlapped, one wait
__device__ __forceinline__ void uc_ld4x16(const unsigned* p0, const unsigned* p1,
                                          const unsigned* p2, const unsigned* p3,
                                          u32x4& a0, u32x4& a1, u32x4& a2, u32x4& a3) {
  asm volatile(
    "global_load_dwordx4 %0, %4, off sc0 sc1\n\t"
    "global_load_dwordx4 %1, %5, off sc0 sc1\n\t"
    "global_load_dwordx4 %2, %6, off sc0 sc1\n\t"
    "global_load_dwordx4 %3, %7, off sc0 sc1\n\t"
    "s_waitcnt vmcnt(0)"
    : "=&v"(a0), "=&v"(a1), "=&v"(a2), "=&v"(a3)
    : "v"(p0), "v"(p1), "v"(p2), "v"(p3)
    : "memory");
  __builtin_amdgcn_sched_barrier(0);
}

// 8x 16B UC loads, one wait
__device__ __forceinline__ void uc_ld8x16(const unsigned* p0, const unsigned* p1,
                                          const unsigned* p2, const unsigned* p3,
                                          const unsigned* p4, const unsigned* p5,
                                          const unsigned* p6, const unsigned* p7,
                                          u32x4& a0, u32x4& a1, u32x4& a2, u32x4& a3,
                                          u32x4& b0, u32x4& b1, u32x4& b2, u32x4& b3) {
  asm volatile(
    "global_load_dwordx4 %0, %8, off sc0 sc1\n\t"
    "global_load_dwordx4 %1, %9, off sc0 sc1\n\t"
    "global_load_dwordx4 %2, %10, off sc0 sc1\n\t"
    "global_load_dwordx4 %3, %11, off sc0 sc1\n\t"
    "global_load_dwordx4 %4, %12, off sc0 sc1\n\t"
    "global_load_dwordx4 %5, %13, off sc0 sc1\n\t"
    "global_load_dwordx4 %6, %14, off sc0 sc1\n\t"
    "global_load_dwordx4 %7, %15, off sc0 sc1\n\t"
    "s_waitcnt vmcnt(0)"
    : "=&v"(a0), "=&v"(a1), "=&v"(a2), "=&v"(a3),
      "=&v"(b0), "=&v"(b1), "=&v"(b2), "=&v"(b3)
    : "v"(p0), "v"(p1), "v"(p2), "v"(p3), "v"(p4), "v"(p5), "v"(p6), "v"(p7)
    : "memory");
  __builtin_amdgcn_sched_barrier(0);
}

__device__ __forceinline__ void uc_st32(unsigned* p, unsigned v) {
  __hip_atomic_store(p, v, __ATOMIC_RELAXED, __HIP_MEMORY_SCOPE_AGENT);
}

// ---------------- prep: build per-(sp,b) timestep lists ----------------
__global__ void prep_kernel(const int* __restrict__ spk, int* __restrict__ tlist,
                            int* __restrict__ len, int* __restrict__ meta) {
  __shared__ int slen[64];
  const int t = threadIdx.x;   // 0..63
  const int sp = t >> 3, b = t & 7;
  int cnt = 0;
  int* tl = tlist + (sp * 8 + b) * SS;
  const int4* srow = (const int4*)(spk + b * SS);
#pragma unroll 4
  for (int i = 0; i < SS / 4; ++i) {
    int4 v = srow[i];
    if (v.x == sp) tl[cnt++] = 4 * i + 0;
    if (v.y == sp) tl[cnt++] = 4 * i + 1;
    if (v.z == sp) tl[cnt++] = 4 * i + 2;
    if (v.w == sp) tl[cnt++] = 4 * i + 3;
  }
  len[t] = cnt;
  slen[t] = cnt;
  for (int i = cnt; i < SS; ++i) tl[i] = 0;  // pad so speculative reads are safe
  __syncthreads();
  if (t < 8) {
    int m = 0;
    for (int i = 0; i < 8; ++i) m = max(m, slen[t * 8 + i]);
    meta[t] = m;
  }
}

// ---------------- persistent GRU kernel, layer-split ----------------
// 256 WGs: L = wg&1 (layer), sp = (wg>>1)&7, og = wg>>4 (16 per (L,sp)).
// Each WG owns 32 outputs j0=og*32 of ONE layer for speaker sp.
// No barriers: tagged ring words ((tag<<16)|f16), consumers poll the data.
// h0 ring: 4 slots; produced by layer0 @round r (slot r&3, tag r+1); consumed by
//   layer0 peers AND layer1 @round r+1. Peer safety is transitive; layer1 safety
//   via the monotonic progress vector (layer0 waits prog>=r-2 before publishing).
// h1 ring: 2 slots, self-contained among layer1 WGs (transitively safe).
__launch_bounds__(256, 1)
__global__ void gru_main(const float* __restrict__ x,
                         const float* __restrict__ Wi, const float* __restrict__ Wh,
                         const float* __restrict__ bi, const float* __restrict__ bh,
                         const int* __restrict__ tlist, const int* __restrict__ len,
                         const int* __restrict__ meta,
                         unsigned* __restrict__ h0ring, unsigned* __restrict__ h1ring,
                         unsigned* __restrict__ prog, float* __restrict__ out) {
  const int wg = blockIdx.x;       // 0..255
  const int L  = wg & 1;
  const int sp = (wg >> 1) & 7;
  const int og = wg >> 4;          // 0..15
  const int j0 = og * 32;
  const int tid = threadIdx.x;
  const int w  = tid >> 6;         // wave 0..3
  const int kw = w & 1;            // K half
  const int nw = w >> 1;           // N half (tiles 3*nw..3*nw+2)
  const int l  = tid & 63;
  const int lr = l & 15;           // A-row (batch) / B-col (weight row in tile)
  const int lg = l >> 4;           // k sub-group
  const int b8 = lr & 7;           // batch row (rows 8-15 duplicate 0-7)

  __shared__ unsigned hstA[8][516];           // staged h0 (tagged)
  __shared__ unsigned hstB[8][516];           // staged h1 (layer1)
  __shared__ float accW[6][2][320];           // Wh·h partials [tile][kw][n*20+m]
  __shared__ float accX2[2][6][2][320];       // L0: x-GEMM dbuf; L1: [0] = Wi1·h0

  // ---- weight preload: fp32 global -> f16 register fragments (done once) ----
  const size_t WMAT = (size_t)G3 * HH;
  const float* pWi = Wi + (size_t)(sp * 2 + L) * WMAT;
  const float* pWh = Wh + (size_t)(sp * 2 + L) * WMAT;
  half8 bwX[3][8], bwH[3][8];     // 96 rows (3 gates x 32 outs), this wave's 3 tiles, K-half
#pragma unroll
  for (int t = 0; t < 3; ++t) {
    const int T6 = 3 * nw + t;
    const int rr = T6 * 16 + lr;                       // 0..95 within slice
    const size_t row = (size_t)((rr >> 5) * HH + j0 + (rr & 31));
#pragma unroll
    for (int q = 0; q < 8; ++q) {
      const int k0 = lg * 8 + (kw * 8 + q) * 32;
      bwX[t][q] = cvt8(pWi + row * HH + k0);
      bwH[t][q] = cvt8(pWh + row * HH + k0);
    }
  }

  // ---- gate-thread metadata: all 256 threads -> (batch gb, output gj) ----
  const int gb = tid >> 5;      // 0..7
  const int gj = tid & 31;      // 0..31
  const int Lb = len[sp * 8 + gb];
  const int* tlB = tlist + (sp * 8 + gb) * SS;
  float bgi[3], bgh[3];
#pragma unroll
  for (int g = 0; g < 3; ++g) {
    bgi[g] = bi[(sp * 2 + L) * G3 + g * HH + j0 + gj];
    bgh[g] = bh[(sp * 2 + L) * G3 + g * HH + j0 + gj];
  }

  // per-lane x-gather metadata (layer0 only; A row b8 supplies batch b8)
  const int* tlX = tlist + (sp * 8 + b8) * SS;
  const float* xrow = x + (size_t)b8 * SS * HH;

  const int R = meta[sp];
  unsigned* progv = prog + sp * 16;
  const int stg_row = tid >> 7;            // staging: chain = 2*i + (tid>>7)
  const int stg_col = 4 * (tid & 127);

  float hprev = 0.f;

  if (L == 0) {
    // ================= LAYER 0 =================
    unsigned r1min = 0;
    // prologue: x-GEMM (Wi0*x_0) into accX2[0]
    {
      const int tx = tlX[0];
      const float* xs = xrow + (size_t)tx * HH;
      half8 xf[8];
      f32x4 a0, a1, a2;
#pragma unroll
      for (int e = 0; e < 4; ++e) { a0[e] = 0.f; a1[e] = 0.f; a2[e] = 0.f; }
#pragma unroll
      for (int q = 0; q < 8; ++q) xf[q] = cvt8(xs + lg * 8 + (kw * 8 + q) * 32);
#pragma unroll
      for (int q = 0; q < 8; ++q) {
        a0 = __builtin_amdgcn_mfma_f32_16x16x32_f16(xf[q], bwX[0][q], a0, 0, 0, 0);
        a1 = __builtin_amdgcn_mfma_f32_16x16x32_f16(xf[q], bwX[1][q], a1, 0, 0, 0);
        a2 = __builtin_amdgcn_mfma_f32_16x16x32_f16(xf[q], bwX[2][q], a2, 0, 0, 0);
      }
      *(f32x4*)&accX2[0][3 * nw + 0][kw][lr * 20 + lg * 4] = a0;
      *(f32x4*)&accX2[0][3 * nw + 1][kw][lr * 20 + lg * 4] = a1;
      *(f32x4*)&accX2[0][3 * nw + 2][kw][lr * 20 + lg * 4] = a2;
    }

    for (int r = 0; r <= R; ++r) {
      // ---- poll h0 (slot (r-1)&3, tag r) and stage ----
      {
        const unsigned exp = (unsigned)r;
        const unsigned* base = h0ring + ((size_t)(((r - 1) & 3) * 64 + sp * 8)) * HH + tid * 4;
        const unsigned *p0 = base, *p1 = base + 1024, *p2 = base + 2048, *p3 = base + 3072;
        u32x4 a0, a1, a2, a3;
        uc_ld4x16(p0, p1, p2, p3, a0, a1, a2, a3);
        unsigned it = 0;
        for (;;) {
          const unsigned bd0 = tagbad(a0, exp), bd1 = tagbad(a1, exp);
          const unsigned bd2 = tagbad(a2, exp), bd3 = tagbad(a3, exp);
          if (!(bd0 | bd1 | bd2 | bd3)) break;
          __builtin_amdgcn_s_sleep(1);
          if (bd0) a0 = uc_ld16(p0);
          if (bd1) a1 = uc_ld16(p1);
          if (bd2) a2 = uc_ld16(p2);
          if (bd3) a3 = uc_ld16(p3);
          if (++it > 2000000u) break;   // safety
        }
        *(u32x4*)&hstA[0 + stg_row][stg_col] = a0;
        *(u32x4*)&hstA[2 + stg_row][stg_col] = a1;
        *(u32x4*)&hstA[4 + stg_row][stg_col] = a2;
        *(u32x4*)&hstA[6 + stg_row][stg_col] = a3;
      }
      __syncthreads();

      // ---- A-frags + 24 MFMA (Wh0*h0) ----
      half8 hA[8];
#pragma unroll
      for (int q = 0; q < 8; ++q) {
        const int k0 = lg * 8 + (kw * 8 + q) * 32;
        hA[q] = pack8(*(const u32x4*)&hstA[b8][k0], *(const u32x4*)&hstA[b8][k0 + 4]);
      }
      f32x4 c0, c1, c2;
#pragma unroll
      for (int e = 0; e < 4; ++e) { c0[e] = 0.f; c1[e] = 0.f; c2[e] = 0.f; }
#pragma unroll
      for (int q = 0; q < 8; ++q) {
        c0 = __builtin_amdgcn_mfma_f32_16x16x32_f16(hA[q], bwH[0][q], c0, 0, 0, 0);
        c1 = __builtin_amdgcn_mfma_f32_16x16x32_f16(hA[q], bwH[1][q], c1, 0, 0, 0);
        c2 = __builtin_amdgcn_mfma_f32_16x16x32_f16(hA[q], bwH[2][q], c2, 0, 0, 0);
      }
      *(f32x4*)&accW[3 * nw + 0][kw][lr * 20 + lg * 4] = c0;
      *(f32x4*)&accW[3 * nw + 1][kw][lr * 20 + lg * 4] = c1;
      *(f32x4*)&accW[3 * nw + 2][kw][lr * 20 + lg * 4] = c2;
      __syncthreads();

      // ---- gates (pos r, active if r < Lb) ----
      if (r < Lb) {
        const int xb = r & 1;
        float gi[3], gh[3];
#pragma unroll
        for (int g = 0; g < 3; ++g) {
          const int T6 = 2 * g + (gj >> 4);
          const int idx = (gj & 15) * 20 + gb;
          gi[g] = accX2[xb][T6][0][idx] + accX2[xb][T6][1][idx] + bgi[g];
          gh[g] = accW[T6][0][idx] + accW[T6][1][idx] + bgh[g];
        }
        const float rr_ = sigm(gi[0] + gh[0]);
        const float zz = sigm(gi[1] + gh[1]);
        const float nn = tanhf(gi[2] + rr_ * gh[2]);
        hprev = (1.f - zz) * nn + zz * hprev;
      }

      // ---- back-pressure: layer1 must have finished round r-3 (prog >= r-2)
      //      before slot r&3 (holding h0_{r-4}) is overwritten ----
      if ((int)r1min < r - 2) {
        unsigned it = 0;
        for (;;) {
          unsigned v = __hip_atomic_load(&progv[tid & 15], __ATOMIC_RELAXED,
                                         __HIP_MEMORY_SCOPE_AGENT);
          v = min(v, (unsigned)__shfl_xor((int)v, 1, 16));
          v = min(v, (unsigned)__shfl_xor((int)v, 2, 16));
          v = min(v, (unsigned)__shfl_xor((int)v, 4, 16));
          v = min(v, (unsigned)__shfl_xor((int)v, 8, 16));
          r1min = v;
          if ((int)r1min >= r - 2) break;
          __builtin_amdgcn_s_sleep(1);
          if (++it > 2000000u) break;  // safety
        }
      }

      // ---- publish h0_r (slot r&3, tag r+1) ----
      {
        union { _Float16 hf; unsigned short us; } cv; cv.hf = (_Float16)hprev;
        uc_st32(&h0ring[((size_t)((r & 3) * 64 + sp * 8 + gb)) * HH + j0 + gj],
                (((unsigned)(r + 1)) << 16) | (unsigned)cv.us);
      }

      // ---- shadow x-GEMM (Wi0*x_{r+1}) into accX2[(r+1)&1]; hides publish latency ----
      {
        const int tx = tlX[(r + 1) & (SS - 1)];
        const float* xs = xrow + (size_t)tx * HH;
        half8 xf[8];
        f32x4 a0, a1, a2;
#pragma unroll
        for (int e = 0; e < 4; ++e) { a0[e] = 0.f; a1[e] = 0.f; a2[e] = 0.f; }
#pragma unroll
        for (int q = 0; q < 8; ++q) xf[q] = cvt8(xs + lg * 8 + (kw * 8 + q) * 32);
#pragma unroll
        for (int q = 0; q < 8; ++q) {
          a0 = __builtin_amdgcn_mfma_f32_16x16x32_f16(xf[q], bwX[0][q], a0, 0, 0, 0);
          a1 = __builtin_amdgcn_mfma_f32_16x16x32_f16(xf[q], bwX[1][q], a1, 0, 0, 0);
          a2 = __builtin_amdgcn_mfma_f32_16x16x32_f16(xf[q], bwX[2][q], a2, 0, 0, 0);
        }
        const int db = (r + 1) & 1;
        *(f32x4*)&accX2[db][3 * nw + 0][kw][lr * 20 + lg * 4] = a0;
        *(f32x4*)&accX2[db][3 * nw + 1][kw][lr * 20 + lg * 4] = a1;
        *(f32x4*)&accX2[db][3 * nw + 2][kw][lr * 20 + lg * 4] = a2;
      }
    }
  } else {
    // ================= LAYER 1 =================
    for (int r = 0; r <= R; ++r) {
      // ---- poll h0 (slot (r-1)&3, tag r) + h1 (slot (r-2)&1, tag r), stage ----
      {
        const unsigned exp = (unsigned)r;
        const unsigned* ba = h0ring + ((size_t)(((r - 1) & 3) * 64 + sp * 8)) * HH + tid * 4;
        const unsigned* bb = h1ring + ((size_t)(((r - 2) & 1) * 64 + sp * 8)) * HH + tid * 4;
        const unsigned *p0 = ba, *p1 = ba + 1024, *p2 = ba + 2048, *p3 = ba + 3072;
        const unsigned *q0 = bb, *q1 = bb + 1024, *q2 = bb + 2048, *q3 = bb + 3072;
        u32x4 a0, a1, a2, a3, d0, d1, d2, d3;
        uc_ld8x16(p0, p1, p2, p3, q0, q1, q2, q3, a0, a1, a2, a3, d0, d1, d2, d3);
        unsigned it = 0;
        for (;;) {
          const unsigned bd0 = tagbad(a0, exp), bd1 = tagbad(a1, exp);
          const unsigned bd2 = tagbad(a2, exp), bd3 = tagbad(a3, exp);
          const unsigned be0 = tagbad(d0, exp), be1 = tagbad(d1, exp);
          const unsigned be2 = tagbad(d2, exp), be3 = tagbad(d3, exp);
          if (!(bd0 | bd1 | bd2 | bd3 | be0 | be1 | be2 | be3)) break;
          __builtin_amdgcn_s_sleep(1);
          if (bd0) a0 = uc_ld16(p0);
          if (bd1) a1 = uc_ld16(p1);
          if (bd2) a2 = uc_ld16(p2);
          if (bd3) a3 = uc_ld16(p3);
          if (be0) d0 = uc_ld16(q0);
          if (be1) d1 = uc_ld16(q1);
          if (be2) d2 = uc_ld16(q2);
          if (be3) d3 = uc_ld16(q3);
          if (++it > 2000000u) break;  // safety
        }
        *(u32x4*)&hstA[0 + stg_row][stg_col] = a0;
        *(u32x4*)&hstA[2 + stg_row][stg_col] = a1;
        *(u32x4*)&hstA[4 + stg_row][stg_col] = a2;
        *(u32x4*)&hstA[6 + stg_row][stg_col] = a3;
        *(u32x4*)&hstB[0 + stg_row][stg_col] = d0;
        *(u32x4*)&hstB[2 + stg_row][stg_col] = d1;
        *(u32x4*)&hstB[4 + stg_row][stg_col] = d2;
        *(u32x4*)&hstB[6 + stg_row][stg_col] = d3;
      }
      __syncthreads();
      // release back-pressure early: our h0_{r-1} reads are done
      if (tid == 0) uc_st32(&progv[og], (unsigned)(r + 1));

      // ---- A-frags + 48 MFMA (Wi1*h0 -> accX2[0], Wh1*h1 -> accW) ----
      half8 hA[8], hB[8];
#pragma unroll
      for (int q = 0; q < 8; ++q) {
        const int k0 = lg * 8 + (kw * 8 + q) * 32;
        hA[q] = pack8(*(const u32x4*)&hstA[b8][k0], *(const u32x4*)&hstA[b8][k0 + 4]);
        hB[q] = pack8(*(const u32x4*)&hstB[b8][k0], *(const u32x4*)&hstB[b8][k0 + 4]);
      }
      f32x4 cA0, cA1, cA2, cB0, cB1, cB2;
#pragma unroll
      for (int e = 0; e < 4; ++e) {
        cA0[e] = 0.f; cA1[e] = 0.f; cA2[e] = 0.f;
        cB0[e] = 0.f; cB1[e] = 0.f; cB2[e] = 0.f;
      }
#pragma unroll
      for (int q = 0; q < 8; ++q) {
        cA0 = __builtin_amdgcn_mfma_f32_16x16x32_f16(hA[q], bwX[0][q], cA0, 0, 0, 0);
        cA1 = __builtin_amdgcn_mfma_f32_16x16x32_f16(hA[q], bwX[1][q], cA1, 0, 0, 0);
        cA2 = __builtin_amdgcn_mfma_f32_16x16x32_f16(hA[q], bwX[2][q], cA2, 0, 0, 0);
        cB0 = __builtin_amdgcn_mfma_f32_16x16x32_f16(hB[q], bwH[0][q], cB0, 0, 0, 0);
        cB1 = __builtin_amdgcn_mfma_f32_16x16x32_f16(hB[q], bwH[1][q], cB1, 0, 0, 0);
        cB2 = __builtin_amdgcn_mfma_f32_16x16x32_f16(hB[q], bwH[2][q], cB2, 0, 0, 0);
      }
      *(f32x4*)&accX2[0][3 * nw + 0][kw][lr * 20 + lg * 4] = cA0;
      *(f32x4*)&accX2[0][3 * nw + 1][kw][lr * 20 + lg * 4] = cA1;
      *(f32x4*)&accX2[0][3 * nw + 2][kw][lr * 20 + lg * 4] = cA2;
      *(f32x4*)&accW[3 * nw + 0][kw][lr * 20 + lg * 4] = cB0;
      *(f32x4*)&accW[3 * nw + 1][kw][lr * 20 + lg * 4] = cB1;
      *(f32x4*)&accW[3 * nw + 2][kw][lr * 20 + lg * 4] = cB2;
      __syncthreads();

      // ---- gates (pos r-1, active if 1 <= r <= Lb) ----
      if (r >= 1 && r <= Lb) {
        float gi[3], gh[3];
#pragma unroll
        for (int g = 0; g < 3; ++g) {
          const int T6 = 2 * g + (gj >> 4);
          const int idx = (gj & 15) * 20 + gb;
          gi[g] = accX2[0][T6][0][idx] + accX2[0][T6][1][idx] + bgi[g];
          gh[g] = accW[T6][0][idx] + accW[T6][1][idx] + bgh[g];
        }
        const float rr_ = sigm(gi[0] + gh[0]);
        const float zz = sigm(gi[1] + gh[1]);
        const float nn = tanhf(gi[2] + rr_ * gh[2]);
        hprev = (1.f - zz) * nn + zz * hprev;
        const int tcur = tlB[(r - 1) & (SS - 1)];
        out[((size_t)(gb * SS + tcur)) * HH + j0 + gj] = hprev;
      }

      // ---- publish h1_{r-1} (slot (r-1)&1, tag r+1) ----
      {
        union { _Float16 hf; unsigned short us; } cv; cv.hf = (_Float16)hprev;
        uc_st32(&h1ring[((size_t)((((r - 1) & 1)) * 64 + sp * 8 + gb)) * HH + j0 + gj],
                (((unsigned)(r + 1)) << 16) | (unsigned)cv.us);
      }
    }
  }
}

extern "C" void kernel_launch(void* const* d_in, const int* in_sizes, int n_in,
                              void* d_out, int out_size, void* d_ws, size_t ws_size,
                              hipStream_t stream) {
  const float* x   = (const float*)d_in[0];
  const int*   spk = (const int*)d_in[1];
  const float* Wi  = (const float*)d_in[2];
  const float* Wh  = (const float*)d_in[3];
  const float* bi  = (const float*)d_in[4];
  const float* bh  = (const float*)d_in[5];
  float* out = (float*)d_out;
  char* ws = (char*)d_ws;

  int*      tlist = (int*)(ws + OFF_TLIST);
  int*      len   = (int*)(ws + OFF_LEN);
  int*      meta  = (int*)(ws + OFF_META);
  unsigned* h0r   = (unsigned*)(ws + OFF_H0);
  unsigned* h1r   = (unsigned*)(ws + OFF_H1);
  unsigned* prog  = (unsigned*)(ws + OFF_PROG);

  (void)in_sizes; (void)n_in; (void)out_size; (void)ws_size;

  // zero rings + progress (tags -> "round -1"); re-done every launch
  hipMemsetAsync(ws + OFF_H0, 0, WS_NEED - OFF_H0, stream);
  prep_kernel<<<1, 64, 0, stream>>>(spk, tlist, len, meta);
  gru_main<<<256, 256, 0, stream>>>(x, Wi, Wh, bi, bh, tlist, len, meta,
                                    h0r, h1r, prog, out);
}